// Round 9
// baseline (262.910 us; speedup 1.0000x reference)
//
#include <hip/hip_runtime.h>
#include <stdint.h>

typedef unsigned short u16;
typedef __attribute__((ext_vector_type(8))) short short8;
typedef __attribute__((ext_vector_type(4))) float f32x4;
typedef __attribute__((ext_vector_type(4))) unsigned short u16x4;

#define S_LEN 2048
#define NH 16
#define DMODEL 1024
#define NR 129
#define LOG2E 1.44269504f

#define MFMA(a,b,c) __builtin_amdgcn_mfma_f32_16x16x32_bf16((a),(b),(c),0,0,0)

__device__ __forceinline__ u16 f2bf(float f){            // RTNE
  uint32_t u = __float_as_uint(f);
  u += 0x7fff + ((u >> 16) & 1);
  return (u16)(u >> 16);
}
__device__ __forceinline__ float bf2f(u16 h){ return __uint_as_float(((uint32_t)h) << 16); }

// packed f32x2 -> bf16x2 (RTNE), single VALU op
__device__ __forceinline__ uint32_t cvtpk(float lo, float hi){
  uint32_t r;
  asm("v_cvt_pk_bf16_f32 %0, %1, %2" : "=v"(r) : "v"(lo), "v"(hi));
  return r;
}

// async global->LDS, 16B per lane; lds dest = wave-uniform base + lane*16 (HW)
__device__ __forceinline__ void gl_lds16(const u16* g, u16* l){
  __builtin_amdgcn_global_load_lds((const __attribute__((address_space(1))) void*)g,
                                   (__attribute__((address_space(3))) void*)l, 16, 0, 0);
}

// ---------------- prep: convx + transw + convemb + mask*log2e ----------------
__global__ __launch_bounds__(256) void k_prep(const float* __restrict__ X,
                                              const float* __restrict__ Wq, const float* __restrict__ Wk,
                                              const float* __restrict__ Wv, const float* __restrict__ Wemb,
                                              const float* __restrict__ mask,
                                              u16* __restrict__ Xb, u16* __restrict__ Wt,
                                              u16* __restrict__ Eb, float* __restrict__ maskL){
  const int bid = blockIdx.x, tid = threadIdx.x;
  if (bid < 4096){
    int i = bid * 256 + tid;
    const float4* xp = (const float4*)X;
    float4 v = xp[i];
    u16x4 o; o.x = f2bf(v.x); o.y = f2bf(v.y); o.z = f2bf(v.z); o.w = f2bf(v.w);
    *(u16x4*)(Xb + (size_t)i * 4) = o;
  } else if (bid < 4864){
    int b2 = bid - 4096;
    int z = b2 >> 8;
    const float* W = (z == 0) ? Wq : (z == 1) ? Wk : Wv;
    u16* Ot = Wt + (size_t)z * 1024 * 1024;
    __shared__ float t[64][65];
    int k0 = ((b2 >> 4) & 15) * 64, n0 = (b2 & 15) * 64;
    int c = tid & 63, r0 = (tid >> 6) * 16;
    #pragma unroll
    for (int i = 0; i < 16; ++i) t[r0 + i][c] = W[(size_t)(k0 + r0 + i) * 1024 + n0 + c];
    __syncthreads();
    #pragma unroll
    for (int i = 0; i < 16; ++i) Ot[(size_t)(n0 + r0 + i) * 1024 + k0 + c] = f2bf(t[c][r0 + i]);
  } else if (bid < 4900){
    int idx = (bid - 4864) * 256 + tid;
    if (idx < 144 * 64){
      int r = idx >> 6;
      Eb[idx] = (r < NR) ? f2bf(Wemb[idx]) : (u16)0;
    }
  } else {
    int idx = (bid - 4900) * 256 + tid;
    maskL[idx] = mask[idx] * LOG2E;
  }
}

// ---------------- QKV GEMM, m97 structure ----------------
// z==0/1 (Q,K): swapped MFMA order -> acc reg = 4 consecutive cols -> u16x4 stores.
// z==2 (V): transposed via LDS staging AND PV-column-permuted within each 64-s block
//   (c = f*16+q*4+r -> c' = q*16+f*4+r), coalesced 16B stores -> VP[g][d][s'].
__global__ __launch_bounds__(256) void k_qkv(const u16* __restrict__ Xb, const u16* __restrict__ Wt,
                                             const float* __restrict__ bq, const float* __restrict__ bk,
                                             const float* __restrict__ bv,
                                             u16* __restrict__ Qs, u16* __restrict__ Kb, u16* __restrict__ Vp){
  const int z = blockIdx.z;
  const u16* W = Wt + (size_t)z * 1024 * 1024;
  const float* bias = (z == 0) ? bq : (z == 1) ? bk : bv;
  const float vs = (z == 0) ? 0.125f * LOG2E : 1.0f;
  const int n0 = blockIdx.x * 128, m0 = blockIdx.y * 128;
  const int tid = threadIdx.x, w = tid >> 6, lane = tid & 63, l15 = lane & 15, quad = lane >> 4;
  const int wm = (w >> 1) * 64, wn = (w & 1) * 64;
  __shared__ __attribute__((aligned(16))) u16 As[128 * 32];
  __shared__ __attribute__((aligned(16))) u16 Bs[128 * 32];
  __shared__ __attribute__((aligned(16))) u16 Ts[64][136];   // z==2 transpose staging
  f32x4 acc[4][4];
  #pragma unroll
  for (int i = 0; i < 4; ++i)
    #pragma unroll
    for (int j = 0; j < 4; ++j) acc[i][j] = (f32x4){0.f,0.f,0.f,0.f};

  const int rA = lane >> 2, cA = (lane & 3) * 8;
  const u16* aBase = Xb + (size_t)(m0 + w * 16 + rA) * 1024 + cA;
  const u16* bBase = W  + (size_t)(n0 + w * 16 + rA) * 1024 + cA;
  u16* aDst0 = As + (w * 16) * 32;  u16* aDst1 = As + (64 + w * 16) * 32;
  u16* bDst0 = Bs + (w * 16) * 32;  u16* bDst1 = Bs + (64 + w * 16) * 32;

  if (z == 2){
    for (int k0 = 0; k0 < 1024; k0 += 32){
      __syncthreads();
      gl_lds16(aBase + k0,             aDst0);
      gl_lds16(aBase + 64 * 1024 + k0, aDst1);
      gl_lds16(bBase + k0,             bDst0);
      gl_lds16(bBase + 64 * 1024 + k0, bDst1);
      __syncthreads();
      short8 af[4], bfr[4];
      #pragma unroll
      for (int f = 0; f < 4; ++f){
        af[f]  = *(const short8*)(As + (wm + f * 16 + l15) * 32 + quad * 8);
        bfr[f] = *(const short8*)(Bs + (wn + f * 16 + l15) * 32 + quad * 8);
      }
      #pragma unroll
      for (int i = 0; i < 4; ++i)
        #pragma unroll
        for (int j = 0; j < 4; ++j) acc[i][j] = MFMA(af[i], bfr[j], acc[i][j]);
    }
    const int hn0 = n0 >> 6;
    const int bb = m0 >> 11, sb = m0 & 2047;
    #pragma unroll
    for (int h2 = 0; h2 < 2; ++h2){
      __syncthreads();
      if ((w & 1) == h2){
        #pragma unroll
        for (int i = 0; i < 4; ++i){
          int sl0 = (w >> 1) * 64 + i * 16 + quad * 4;   // local s in 0..127
          #pragma unroll
          for (int j = 0; j < 4; ++j){
            int d = j * 16 + l15;
            float bsv = bias[n0 + h2 * 64 + d];
            u16x4 vv;
            #pragma unroll
            for (int r = 0; r < 4; ++r) vv[r] = f2bf(acc[i][j][r] + bsv);
            *(u16x4*)&Ts[d][sl0] = vv;
          }
        }
      }
      __syncthreads();
      // permuted cooperative store: dest chunk m (16B) pulls two 8B source groups
      size_t gbase = ((size_t)(bb * 16 + hn0 + h2) * 64) * S_LEN + sb;
      #pragma unroll
      for (int it = 0; it < 4; ++it){
        int c2 = tid + it * 256;
        int d = c2 >> 4, m = c2 & 15;
        int blk = (m >> 3) * 64, mb = m & 7;
        int q = mb >> 1, f = (mb & 1) * 2;
        const u16* lo = &Ts[d][blk + f * 16 + q * 4];
        const u16* hi = &Ts[d][blk + (f + 1) * 16 + q * 4];
        short8 vv;
        #pragma unroll
        for (int u = 0; u < 4; ++u){ vv[u] = (short)lo[u]; vv[4 + u] = (short)hi[u]; }
        *(short8*)(Vp + gbase + (size_t)d * S_LEN + blk + mb * 8) = vv;
      }
    }
  } else {
    for (int k0 = 0; k0 < 1024; k0 += 32){
      __syncthreads();
      gl_lds16(aBase + k0,             aDst0);
      gl_lds16(aBase + 64 * 1024 + k0, aDst1);
      gl_lds16(bBase + k0,             bDst0);
      gl_lds16(bBase + 64 * 1024 + k0, bDst1);
      __syncthreads();
      short8 af[4], bfr[4];
      #pragma unroll
      for (int f = 0; f < 4; ++f){
        af[f]  = *(const short8*)(As + (wm + f * 16 + l15) * 32 + quad * 8);
        bfr[f] = *(const short8*)(Bs + (wn + f * 16 + l15) * 32 + quad * 8);
      }
      #pragma unroll
      for (int i = 0; i < 4; ++i)
        #pragma unroll
        for (int j = 0; j < 4; ++j) acc[i][j] = MFMA(bfr[j], af[i], acc[i][j]);  // D[n][m]
    }
    u16* outp = (z == 0) ? Qs : Kb;
    #pragma unroll
    for (int i = 0; i < 4; ++i){
      int srow = m0 + wm + i * 16 + l15;
      int bb = srow >> 11, s = srow & 2047;
      #pragma unroll
      for (int j = 0; j < 4; ++j){
        int coln = n0 + wn + j * 16 + quad * 4;
        f32x4 bsv4 = *(const f32x4*)&bias[coln];
        int hh = coln >> 6, jd = coln & 63;
        u16x4 ov;
        #pragma unroll
        for (int r = 0; r < 4; ++r) ov[r] = f2bf((acc[i][j][r] + bsv4[r]) * vs);
        *(u16x4*)(outp + (((size_t)(bb * 16 + hh)) * S_LEN + s) * 64 + jd) = ov;
      }
    }
  }
}

// ---------------- fused flash + rel_v band ----------------
// Round 9: R7 kernel with SINGLE K/V buffer -> LDS 32,768 B -> 5 blocks/CU
// (20 waves/CU). Exposed DMA drain per tile is covered by cross-block TLP.
// launch_bounds(256,5): VGPR cap 102 > ~84 needed -> no spill (R8 lesson).
// Tail overlays: Psb[64][128] over K/V, Evs[64][128] over QEb (exact-size unions).
__global__ __launch_bounds__(256, 5) void k_flash(const u16* __restrict__ QS, const u16* __restrict__ KB,
                                                  const u16* __restrict__ VP, const u16* __restrict__ EMBK,
                                                  const float* __restrict__ maskL, const float* __restrict__ embv,
                                                  float* __restrict__ out){
  const int g = blockIdx.y; const int b = g >> 4; const int h = g & 15;
  const int q0 = blockIdx.x * 64;
  const int tid = threadIdx.x;
  const int w = tid >> 6; const int lane = tid & 63;
  const int l15 = lane & 15; const int quad = lane >> 4;
  const int wm = w * 16;
  const int rqb = quad * 4;
  const int qrow = q0 + wm + l15;

  __shared__ union U1 {
    struct {
      __attribute__((aligned(16))) u16 K[4096];
      __attribute__((aligned(16))) u16 V[4096];
    } s;                                             // 16,384 (main loop)
    __attribute__((aligned(16))) u16 Psb[64][128];   // 16,384 (tail overlay)
  } uu;
  __shared__ union U2 {
    __attribute__((aligned(16))) u16 QEb[4][16][128];  // 16,384 (main loop)
    __attribute__((aligned(16))) u16 Evs[64][128];     // 16,384 (tail overlay)
  } qq;                                                // total 32,768 -> 5 blk/CU

  // ---- staging geometry (R7-validated) ----
  const int lrow = lane >> 3;
  const int lsw  = ((lane & 7) ^ lrow) * 8;          // inverse-swizzled source granule
  const u16* kS = KB + ((size_t)g * S_LEN + w * 16 + lrow) * 64 + lsw;
  const u16* vS = VP + ((size_t)(g * 64 + w * 16 + lrow)) * S_LEN + lsw;
  const float* mBase = maskL + b * S_LEN;

  // prologue: DMA tile 0 (covered by qe-MFMA below)
  {
    u16* kd = uu.s.K + (w * 16) * 64;
    u16* vd = uu.s.V + (w * 16) * 64;
    gl_lds16(kS,             kd);
    gl_lds16(kS + 8 * 64,    kd + 512);
    gl_lds16(vS,             vd);
    gl_lds16(vS + 8 * S_LEN, vd + 512);
  }

  f32x4 mcur[4];
  #pragma unroll
  for (int fn = 0; fn < 4; ++fn) mcur[fn] = *(const f32x4*)(mBase + fn * 16 + rqb);

  const u16* qptr = QS + ((size_t)g * S_LEN + q0 + wm + l15) * 64 + quad * 8;
  short8 qa0 = *(const short8*)qptr;
  short8 qa1 = *(const short8*)(qptr + 32);

  // qe = Q @ emb_k^T; cols 0..127 -> QEb; col 128 -> regs via shfl
  float qeLf = 0.f;
  #pragma unroll
  for (int fn = 0; fn < 9; ++fn){
    const u16* ep = EMBK + (fn * 16 + l15) * 64 + quad * 8;
    short8 eb0 = *(const short8*)ep;
    short8 eb1 = *(const short8*)(ep + 32);
    f32x4 c = (f32x4){0.f,0.f,0.f,0.f};
    c = MFMA(qa0, eb0, c);
    c = MFMA(qa1, eb1, c);
    if (fn < 8){
      #pragma unroll
      for (int r = 0; r < 4; ++r) qq.QEb[w][rqb + r][fn * 16 + l15] = f2bf(c[r]);
    } else {
      int srcl = (l15 >> 2) << 4;
      float t0 = __shfl(c[0], srcl, 64);
      float t1 = __shfl(c[1], srcl, 64);
      float t2 = __shfl(c[2], srcl, 64);
      float t3 = __shfl(c[3], srcl, 64);
      int rr = l15 & 3;
      float qv = (rr == 0) ? t0 : (rr == 1) ? t1 : (rr == 2) ? t2 : t3;
      qeLf = bf2f(f2bf(qv));
    }
  }
  __syncthreads();   // drains vmcnt (tile-0 DMA) + lgkm (QEb)

  const float qeR = bf2f(qq.QEb[w][l15][0]);
  const float qeL = qeLf;

  // ones-column B fragment for MFMA row-sums
  short8 bones;
  {
    short one = (l15 == 0) ? (short)0x3F80 : (short)0;
    #pragma unroll
    for (int j = 0; j < 8; ++j) bones[j] = one;
  }

  // swizzled read offsets (u16 units)
  const int rsw = l15 & 7;
  const int kO0 = ((quad     ^ rsw) * 8);
  const int kO1 = (((quad+4) ^ rsw) * 8);
  const int vO0 = (((quad*2)     ^ rsw) * 8);
  const int vO1 = (((quad*2 + 1) ^ rsw) * 8);

  f32x4 o[4];
  #pragma unroll
  for (int f = 0; f < 4; ++f) o[f] = (f32x4){0.f,0.f,0.f,0.f};
  f32x4 lacc = (f32x4){0.f,0.f,0.f,0.f};
  float ll0v[4] = {0.f,0.f,0.f,0.f};
  float ll_mx = 0.f;
  float rsb_s = 0.f;
  uint32_t st0[8] = {0,0,0,0,0,0,0,0};   // band stashes (bf16 pairs), static idx only
  uint32_t st1[8] = {0,0,0,0,0,0,0,0};
  uint32_t st2[8] = {0,0,0,0,0,0,0,0};

  for (int kt = 0; kt < S_LEN; kt += 64){
    const int ktn = kt + 64;

    const bool leftC  = (kt <= q0 - 128);
    const bool rightC = (kt >= q0 + 128);
    const float qeadd = leftC ? qeL : (rightC ? qeR : 0.f);

    // QK^T from LDS K; C-init = mask(+qe)
    const u16* ks = uu.s.K;
    f32x4 p4[4];
    __builtin_amdgcn_s_setprio(1);
    #pragma unroll
    for (int fn = 0; fn < 4; ++fn){
      const u16* krow = ks + (fn * 16 + l15) * 64;
      short8 kb0 = *(const short8*)(krow + kO0);
      short8 kb1 = *(const short8*)(krow + kO1);
      f32x4 c = mcur[fn] + qeadd;
      c = MFMA(kb0, qa0, c);
      c = MFMA(kb1, qa1, c);
      p4[fn] = c;
    }
    __builtin_amdgcn_s_setprio(0);

    // prefetch next mask
    f32x4 mnext[4];
    if (ktn < S_LEN){
      #pragma unroll
      for (int fn = 0; fn < 4; ++fn) mnext[fn] = *(const f32x4*)(mBase + ktn + fn * 16 + rqb);
    }

    if (leftC | rightC){
      #pragma unroll
      for (int fn = 0; fn < 4; ++fn)
        #pragma unroll
        for (int r = 0; r < 4; ++r) p4[fn][r] = __builtin_amdgcn_exp2f(p4[fn][r]);
    } else {
      // mixed: per-element qe gather; band sums only (P stashed in PV pack below)
      #pragma unroll
      for (int fn = 0; fn < 4; ++fn){
        int kbase = kt + fn * 16 + rqb;
        #pragma unroll
        for (int r = 0; r < 4; ++r){
          int dq = qrow - (kbase + r) + 64;
          int ridx = min(max(dq, 0), 127);
          float qv = (dq >= 128) ? qeL : bf2f(qq.QEb[w][l15][ridx]);
          float p = __builtin_amdgcn_exp2f(p4[fn][r] + qv);
          ll_mx += (dq >= 128) ? p : 0.f;
          rsb_s += (dq >= 1 && dq <= 127) ? p : 0.f;
          p4[fn][r] = p;
        }
      }
    }

    // pack P, stash band tiles, MFMA row-sum, PV
    __builtin_amdgcn_s_setprio(1);
    const u16* vsb = uu.s.V;
    #pragma unroll
    for (int fp = 0; fp < 2; ++fp){
      union { uint32_t u[4]; short8 s8; } pk;
      pk.u[0] = cvtpk(p4[2 * fp][0],     p4[2 * fp][1]);
      pk.u[1] = cvtpk(p4[2 * fp][2],     p4[2 * fp][3]);
      pk.u[2] = cvtpk(p4[2 * fp + 1][0], p4[2 * fp + 1][1]);
      pk.u[3] = cvtpk(p4[2 * fp + 1][2], p4[2 * fp + 1][3]);
      if (kt == q0 - 64){
        #pragma unroll
        for (int u4 = 0; u4 < 4; ++u4) st0[fp * 4 + u4] = pk.u[u4];
      } else if (kt == q0){
        #pragma unroll
        for (int u4 = 0; u4 < 4; ++u4) st1[fp * 4 + u4] = pk.u[u4];
      } else if (kt == q0 + 64){
        #pragma unroll
        for (int u4 = 0; u4 < 4; ++u4) st2[fp * 4 + u4] = pk.u[u4];
      }
      short8 pa = pk.s8;
      lacc = MFMA(pa, bones, lacc);
      const int vO = fp ? vO1 : vO0;
      #pragma unroll
      for (int fd = 0; fd < 4; ++fd){
        short8 vb = *(const short8*)(vsb + (fd * 16 + l15) * 64 + vO);
        o[fd] = MFMA(pa, vb, o[fd]);
      }
    }
    __builtin_amdgcn_s_setprio(0);

    if (kt == q0 - 128){
      #pragma unroll
      for (int r = 0; r < 4; ++r) ll0v[r] = lacc[r];
    }
    if (ktn < S_LEN){
      #pragma unroll
      for (int fn = 0; fn < 4; ++fn) mcur[fn] = mnext[fn];
      __syncthreads();   // all reads of this tile done
      u16* kd = uu.s.K + (w * 16) * 64;
      u16* vd = uu.s.V + (w * 16) * 64;
      gl_lds16(kS + (size_t)ktn * 64,       kd);
      gl_lds16(kS + (size_t)(ktn + 8) * 64, kd + 512);
      gl_lds16(vS + ktn,                    vd);
      gl_lds16(vS + ktn + 8 * S_LEN,        vd + 512);
      __syncthreads();   // drains DMA -> next tile visible (TLP covers the stall)
    }
  }

  // ---- tail: overlay Psb/Evs onto dead LDS ----
  __syncthreads();   // all K/V & QEb reads complete before overwrite
  {
    short8 z8 = (short8){0,0,0,0,0,0,0,0};
    #pragma unroll
    for (int i = 0; i < 4; ++i) ((short8*)uu.Psb)[tid + i * 256] = z8;
    int d = tid & 63, t4 = tid >> 6;
    #pragma unroll
    for (int it = 0; it < 32; ++it){
      int t = t4 + it * 4;
      float v = (t <= 126) ? embv[(size_t)(127 - t) * 64 + d] : 0.f;
      qq.Evs[d][(((t >> 3) ^ (d & 7)) << 3) | (t & 7)] = f2bf(v);
    }
  }
  __syncthreads();

  // band writes from stash (swizzled Psb, same key as reads: row&7 = l15&7)
  auto bandw = [&](int ktb, const uint32_t* st){
    #pragma unroll
    for (int fn = 0; fn < 4; ++fn)
      #pragma unroll
      for (int r = 0; r < 4; ++r){
        int dq = qrow - (ktb + fn * 16 + rqb + r) + 64;
        if (dq >= 1 && dq <= 127){
          int t = 127 - dq;
          uu.Psb[wm + l15][(((t >> 3) ^ rsw) << 3) | (t & 7)] =
            (u16)(st[(fn >> 1) * 4 + (fn & 1) * 2 + (r >> 1)] >> ((r & 1) * 16));
        }
      }
  };
  if (q0 >= 64) bandw(q0 - 64, st0);
  bandw(q0, st1);
  if (q0 + 64 < S_LEN) bandw(q0 + 64, st2);
  __syncthreads();

  // tail MFMA: ob = Psb_band @ Evs
  f32x4 ob[4];
  #pragma unroll
  for (int f = 0; f < 4; ++f) ob[f] = (f32x4){0.f,0.f,0.f,0.f};
  #pragma unroll
  for (int kb = 0; kb < 4; ++kb){
    const int go = ((kb * 4 + quad) ^ rsw) << 3;
    short8 pa = *(const short8*)&uu.Psb[wm + l15][go];
    #pragma unroll
    for (int fd = 0; fd < 4; ++fd){
      short8 vb = *(const short8*)&qq.Evs[fd * 16 + l15][go];
      ob[fd] = MFMA(pa, vb, ob[fd]);
    }
  }

  // final reductions
  #pragma unroll
  for (int st = 16; st < 64; st <<= 1){
    ll_mx += __shfl_xor(ll_mx, st, 64);
    rsb_s += __shfl_xor(rsb_s, st, 64);
  }

  float inv[4], tl[4], trr[4];
  #pragma unroll
  for (int r = 0; r < 4; ++r){
    float L   = __shfl(lacc[r], quad << 4);
    float l0  = __shfl(ll0v[r], quad << 4);
    int src   = (quad << 4) + rqb + r;
    float lmx = __shfl(ll_mx, src);
    float rv  = __shfl(rsb_s, src);
    inv[r] = 1.f / L;
    tl[r]  = (l0 + lmx) * inv[r];
    trr[r] = 1.f - tl[r] - rv * inv[r];
  }

  #pragma unroll
  for (int fd = 0; fd < 4; ++fd){
    int dim = fd * 16 + l15;
    float evL = embv[(size_t)128 * 64 + dim];
    float evR = embv[dim];
    #pragma unroll
    for (int r = 0; r < 4; ++r){
      int row = q0 + wm + rqb + r;
      float val = (o[fd][r] + ob[fd][r]) * inv[r] + tl[r] * evL + trr[r] * evR;
      out[((size_t)(b * S_LEN + row)) * DMODEL + h * 64 + dim] = val;
    }
  }
}

extern "C" void kernel_launch(void* const* d_in, const int* in_sizes, int n_in,
                              void* d_out, int out_size, void* d_ws, size_t ws_size,
                              hipStream_t stream){
  const float* X    = (const float*)d_in[0];
  const float* mask = (const float*)d_in[1];
  const float* Wq   = (const float*)d_in[2];
  const float* bq   = (const float*)d_in[3];
  const float* Wk   = (const float*)d_in[4];
  const float* bk   = (const float*)d_in[5];
  const float* Wv   = (const float*)d_in[6];
  const float* bv   = (const float*)d_in[7];
  const float* embk = (const float*)d_in[8];
  const float* embv = (const float*)d_in[9];
  float* out = (float*)d_out;
  char* ws = (char*)d_ws;

  u16* XB   = (u16*)(ws + 0);            // 8,388,608
  u16* WT   = (u16*)(ws + 8388608);      // 6,291,456
  u16* EKB  = (u16*)(ws + 14680064);     // 18,432
  u16* QS   = (u16*)(ws + 14698496);     // 8,388,608
  u16* KB   = (u16*)(ws + 23087104);     // 8,388,608
  u16* VP   = (u16*)(ws + 31475712);     // 8,388,608 (transposed + PV-permuted V)
  float* MSL = (float*)(ws + 48252928);  // 16,384  (end 48,269,312)

  k_prep   <<<4916, 256, 0, stream>>>(X, Wq, Wk, Wv, embk, mask, XB, WT, EKB, MSL);
  k_qkv    <<<dim3(8, 32, 3), 256, 0, stream>>>(XB, WT, bq, bk, bv, QS, KB, VP);
  k_flash  <<<dim3(32, 32), 256, 0, stream>>>(QS, KB, VP, EKB, MSL, embv, out);
}

// Round 10
// 214.706 us; speedup vs baseline: 1.2245x; 1.2245x over previous
//
#include <hip/hip_runtime.h>
#include <stdint.h>

typedef unsigned short u16;
typedef __attribute__((ext_vector_type(8))) short short8;
typedef __attribute__((ext_vector_type(4))) float f32x4;
typedef __attribute__((ext_vector_type(4))) unsigned short u16x4;

#define S_LEN 2048
#define NH 16
#define DMODEL 1024
#define NR 129
#define LOG2E 1.44269504f

#define MFMA(a,b,c) __builtin_amdgcn_mfma_f32_16x16x32_bf16((a),(b),(c),0,0,0)

__device__ __forceinline__ u16 f2bf(float f){            // RTNE
  uint32_t u = __float_as_uint(f);
  u += 0x7fff + ((u >> 16) & 1);
  return (u16)(u >> 16);
}
__device__ __forceinline__ float bf2f(u16 h){ return __uint_as_float(((uint32_t)h) << 16); }

// packed f32x2 -> bf16x2 (RTNE), single VALU op
__device__ __forceinline__ uint32_t cvtpk(float lo, float hi){
  uint32_t r;
  asm("v_cvt_pk_bf16_f32 %0, %1, %2" : "=v"(r) : "v"(lo), "v"(hi));
  return r;
}

// async global->LDS, 16B per lane; lds dest = wave-uniform base + lane*16 (HW)
__device__ __forceinline__ void gl_lds16(const u16* g, u16* l){
  __builtin_amdgcn_global_load_lds((const __attribute__((address_space(1))) void*)g,
                                   (__attribute__((address_space(3))) void*)l, 16, 0, 0);
}

// ---------------- prep: convx + transw + convemb + mask*log2e ----------------
__global__ __launch_bounds__(256) void k_prep(const float* __restrict__ X,
                                              const float* __restrict__ Wq, const float* __restrict__ Wk,
                                              const float* __restrict__ Wv, const float* __restrict__ Wemb,
                                              const float* __restrict__ mask,
                                              u16* __restrict__ Xb, u16* __restrict__ Wt,
                                              u16* __restrict__ Eb, float* __restrict__ maskL){
  const int bid = blockIdx.x, tid = threadIdx.x;
  if (bid < 4096){
    int i = bid * 256 + tid;
    const float4* xp = (const float4*)X;
    float4 v = xp[i];
    u16x4 o; o.x = f2bf(v.x); o.y = f2bf(v.y); o.z = f2bf(v.z); o.w = f2bf(v.w);
    *(u16x4*)(Xb + (size_t)i * 4) = o;
  } else if (bid < 4864){
    int b2 = bid - 4096;
    int z = b2 >> 8;
    const float* W = (z == 0) ? Wq : (z == 1) ? Wk : Wv;
    u16* Ot = Wt + (size_t)z * 1024 * 1024;
    __shared__ float t[64][65];
    int k0 = ((b2 >> 4) & 15) * 64, n0 = (b2 & 15) * 64;
    int c = tid & 63, r0 = (tid >> 6) * 16;
    #pragma unroll
    for (int i = 0; i < 16; ++i) t[r0 + i][c] = W[(size_t)(k0 + r0 + i) * 1024 + n0 + c];
    __syncthreads();
    #pragma unroll
    for (int i = 0; i < 16; ++i) Ot[(size_t)(n0 + r0 + i) * 1024 + k0 + c] = f2bf(t[c][r0 + i]);
  } else if (bid < 4900){
    int idx = (bid - 4864) * 256 + tid;
    if (idx < 144 * 64){
      int r = idx >> 6;
      Eb[idx] = (r < NR) ? f2bf(Wemb[idx]) : (u16)0;
    }
  } else {
    int idx = (bid - 4900) * 256 + tid;
    maskL[idx] = mask[idx] * LOG2E;
  }
}

// ---------------- QKV GEMM, m97 structure ----------------
// z==0/1 (Q,K): swapped MFMA order -> acc reg = 4 consecutive cols -> u16x4 stores.
// z==2 (V): transposed via LDS staging AND PV-column-permuted within each 64-s block
//   (c = f*16+q*4+r -> c' = q*16+f*4+r), coalesced 16B stores -> VP[g][d][s'].
__global__ __launch_bounds__(256) void k_qkv(const u16* __restrict__ Xb, const u16* __restrict__ Wt,
                                             const float* __restrict__ bq, const float* __restrict__ bk,
                                             const float* __restrict__ bv,
                                             u16* __restrict__ Qs, u16* __restrict__ Kb, u16* __restrict__ Vp){
  const int z = blockIdx.z;
  const u16* W = Wt + (size_t)z * 1024 * 1024;
  const float* bias = (z == 0) ? bq : (z == 1) ? bk : bv;
  const float vs = (z == 0) ? 0.125f * LOG2E : 1.0f;
  const int n0 = blockIdx.x * 128, m0 = blockIdx.y * 128;
  const int tid = threadIdx.x, w = tid >> 6, lane = tid & 63, l15 = lane & 15, quad = lane >> 4;
  const int wm = (w >> 1) * 64, wn = (w & 1) * 64;
  __shared__ __attribute__((aligned(16))) u16 As[128 * 32];
  __shared__ __attribute__((aligned(16))) u16 Bs[128 * 32];
  __shared__ __attribute__((aligned(16))) u16 Ts[64][136];   // z==2 transpose staging
  f32x4 acc[4][4];
  #pragma unroll
  for (int i = 0; i < 4; ++i)
    #pragma unroll
    for (int j = 0; j < 4; ++j) acc[i][j] = (f32x4){0.f,0.f,0.f,0.f};

  const int rA = lane >> 2, cA = (lane & 3) * 8;
  const u16* aBase = Xb + (size_t)(m0 + w * 16 + rA) * 1024 + cA;
  const u16* bBase = W  + (size_t)(n0 + w * 16 + rA) * 1024 + cA;
  u16* aDst0 = As + (w * 16) * 32;  u16* aDst1 = As + (64 + w * 16) * 32;
  u16* bDst0 = Bs + (w * 16) * 32;  u16* bDst1 = Bs + (64 + w * 16) * 32;

  if (z == 2){
    for (int k0 = 0; k0 < 1024; k0 += 32){
      __syncthreads();
      gl_lds16(aBase + k0,             aDst0);
      gl_lds16(aBase + 64 * 1024 + k0, aDst1);
      gl_lds16(bBase + k0,             bDst0);
      gl_lds16(bBase + 64 * 1024 + k0, bDst1);
      __syncthreads();
      short8 af[4], bfr[4];
      #pragma unroll
      for (int f = 0; f < 4; ++f){
        af[f]  = *(const short8*)(As + (wm + f * 16 + l15) * 32 + quad * 8);
        bfr[f] = *(const short8*)(Bs + (wn + f * 16 + l15) * 32 + quad * 8);
      }
      #pragma unroll
      for (int i = 0; i < 4; ++i)
        #pragma unroll
        for (int j = 0; j < 4; ++j) acc[i][j] = MFMA(af[i], bfr[j], acc[i][j]);
    }
    const int hn0 = n0 >> 6;
    const int bb = m0 >> 11, sb = m0 & 2047;
    #pragma unroll
    for (int h2 = 0; h2 < 2; ++h2){
      __syncthreads();
      if ((w & 1) == h2){
        #pragma unroll
        for (int i = 0; i < 4; ++i){
          int sl0 = (w >> 1) * 64 + i * 16 + quad * 4;   // local s in 0..127
          #pragma unroll
          for (int j = 0; j < 4; ++j){
            int d = j * 16 + l15;
            float bsv = bias[n0 + h2 * 64 + d];
            u16x4 vv;
            #pragma unroll
            for (int r = 0; r < 4; ++r) vv[r] = f2bf(acc[i][j][r] + bsv);
            *(u16x4*)&Ts[d][sl0] = vv;
          }
        }
      }
      __syncthreads();
      // permuted cooperative store: dest chunk m (16B) pulls two 8B source groups
      size_t gbase = ((size_t)(bb * 16 + hn0 + h2) * 64) * S_LEN + sb;
      #pragma unroll
      for (int it = 0; it < 4; ++it){
        int c2 = tid + it * 256;
        int d = c2 >> 4, m = c2 & 15;
        int blk = (m >> 3) * 64, mb = m & 7;
        int q = mb >> 1, f = (mb & 1) * 2;
        const u16* lo = &Ts[d][blk + f * 16 + q * 4];
        const u16* hi = &Ts[d][blk + (f + 1) * 16 + q * 4];
        short8 vv;
        #pragma unroll
        for (int u = 0; u < 4; ++u){ vv[u] = (short)lo[u]; vv[4 + u] = (short)hi[u]; }
        *(short8*)(Vp + gbase + (size_t)d * S_LEN + blk + mb * 8) = vv;
      }
    }
  } else {
    for (int k0 = 0; k0 < 1024; k0 += 32){
      __syncthreads();
      gl_lds16(aBase + k0,             aDst0);
      gl_lds16(aBase + 64 * 1024 + k0, aDst1);
      gl_lds16(bBase + k0,             bDst0);
      gl_lds16(bBase + 64 * 1024 + k0, bDst1);
      __syncthreads();
      short8 af[4], bfr[4];
      #pragma unroll
      for (int f = 0; f < 4; ++f){
        af[f]  = *(const short8*)(As + (wm + f * 16 + l15) * 32 + quad * 8);
        bfr[f] = *(const short8*)(Bs + (wn + f * 16 + l15) * 32 + quad * 8);
      }
      #pragma unroll
      for (int i = 0; i < 4; ++i)
        #pragma unroll
        for (int j = 0; j < 4; ++j) acc[i][j] = MFMA(bfr[j], af[i], acc[i][j]);  // D[n][m]
    }
    u16* outp = (z == 0) ? Qs : Kb;
    #pragma unroll
    for (int i = 0; i < 4; ++i){
      int srow = m0 + wm + i * 16 + l15;
      int bb = srow >> 11, s = srow & 2047;
      #pragma unroll
      for (int j = 0; j < 4; ++j){
        int coln = n0 + wn + j * 16 + quad * 4;
        f32x4 bsv4 = *(const f32x4*)&bias[coln];
        int hh = coln >> 6, jd = coln & 63;
        u16x4 ov;
        #pragma unroll
        for (int r = 0; r < 4; ++r) ov[r] = f2bf((acc[i][j][r] + bsv4[r]) * vs);
        *(u16x4*)(outp + (((size_t)(bb * 16 + hh)) * S_LEN + s) * 64 + jd) = ov;
      }
    }
  }
}

// ---------------- fused flash + rel_v band ----------------
// Round 10: R9 kernel, one change: __launch_bounds__(256, 4) -> VGPR cap 128
// (kernel needs ~84; R9's (256,5) cap forced 48 + spills, WRITE 129MB).
// Single K/V buffer, LDS 32,768 B; VGPR tier 65..128 allows 16 waves/CU
// -> 4 blocks/CU, clean registers. Exposed DMA drain covered by TLP.
__global__ __launch_bounds__(256, 4) void k_flash(const u16* __restrict__ QS, const u16* __restrict__ KB,
                                                  const u16* __restrict__ VP, const u16* __restrict__ EMBK,
                                                  const float* __restrict__ maskL, const float* __restrict__ embv,
                                                  float* __restrict__ out){
  const int g = blockIdx.y; const int b = g >> 4; const int h = g & 15;
  const int q0 = blockIdx.x * 64;
  const int tid = threadIdx.x;
  const int w = tid >> 6; const int lane = tid & 63;
  const int l15 = lane & 15; const int quad = lane >> 4;
  const int wm = w * 16;
  const int rqb = quad * 4;
  const int qrow = q0 + wm + l15;

  __shared__ union U1 {
    struct {
      __attribute__((aligned(16))) u16 K[4096];
      __attribute__((aligned(16))) u16 V[4096];
    } s;                                             // 16,384 (main loop)
    __attribute__((aligned(16))) u16 Psb[64][128];   // 16,384 (tail overlay)
  } uu;
  __shared__ union U2 {
    __attribute__((aligned(16))) u16 QEb[4][16][128];  // 16,384 (main loop)
    __attribute__((aligned(16))) u16 Evs[64][128];     // 16,384 (tail overlay)
  } qq;                                                // total 32,768

  // ---- staging geometry (R7-validated) ----
  const int lrow = lane >> 3;
  const int lsw  = ((lane & 7) ^ lrow) * 8;          // inverse-swizzled source granule
  const u16* kS = KB + ((size_t)g * S_LEN + w * 16 + lrow) * 64 + lsw;
  const u16* vS = VP + ((size_t)(g * 64 + w * 16 + lrow)) * S_LEN + lsw;
  const float* mBase = maskL + b * S_LEN;

  // prologue: DMA tile 0 (covered by qe-MFMA below)
  {
    u16* kd = uu.s.K + (w * 16) * 64;
    u16* vd = uu.s.V + (w * 16) * 64;
    gl_lds16(kS,             kd);
    gl_lds16(kS + 8 * 64,    kd + 512);
    gl_lds16(vS,             vd);
    gl_lds16(vS + 8 * S_LEN, vd + 512);
  }

  f32x4 mcur[4];
  #pragma unroll
  for (int fn = 0; fn < 4; ++fn) mcur[fn] = *(const f32x4*)(mBase + fn * 16 + rqb);

  const u16* qptr = QS + ((size_t)g * S_LEN + q0 + wm + l15) * 64 + quad * 8;
  short8 qa0 = *(const short8*)qptr;
  short8 qa1 = *(const short8*)(qptr + 32);

  // qe = Q @ emb_k^T; cols 0..127 -> QEb; col 128 -> regs via shfl
  float qeLf = 0.f;
  #pragma unroll
  for (int fn = 0; fn < 9; ++fn){
    const u16* ep = EMBK + (fn * 16 + l15) * 64 + quad * 8;
    short8 eb0 = *(const short8*)ep;
    short8 eb1 = *(const short8*)(ep + 32);
    f32x4 c = (f32x4){0.f,0.f,0.f,0.f};
    c = MFMA(qa0, eb0, c);
    c = MFMA(qa1, eb1, c);
    if (fn < 8){
      #pragma unroll
      for (int r = 0; r < 4; ++r) qq.QEb[w][rqb + r][fn * 16 + l15] = f2bf(c[r]);
    } else {
      int srcl = (l15 >> 2) << 4;
      float t0 = __shfl(c[0], srcl, 64);
      float t1 = __shfl(c[1], srcl, 64);
      float t2 = __shfl(c[2], srcl, 64);
      float t3 = __shfl(c[3], srcl, 64);
      int rr = l15 & 3;
      float qv = (rr == 0) ? t0 : (rr == 1) ? t1 : (rr == 2) ? t2 : t3;
      qeLf = bf2f(f2bf(qv));
    }
  }
  __syncthreads();   // drains vmcnt (tile-0 DMA) + lgkm (QEb)

  const float qeR = bf2f(qq.QEb[w][l15][0]);
  const float qeL = qeLf;

  // ones-column B fragment for MFMA row-sums
  short8 bones;
  {
    short one = (l15 == 0) ? (short)0x3F80 : (short)0;
    #pragma unroll
    for (int j = 0; j < 8; ++j) bones[j] = one;
  }

  // swizzled read offsets (u16 units)
  const int rsw = l15 & 7;
  const int kO0 = ((quad     ^ rsw) * 8);
  const int kO1 = (((quad+4) ^ rsw) * 8);
  const int vO0 = (((quad*2)     ^ rsw) * 8);
  const int vO1 = (((quad*2 + 1) ^ rsw) * 8);

  f32x4 o[4];
  #pragma unroll
  for (int f = 0; f < 4; ++f) o[f] = (f32x4){0.f,0.f,0.f,0.f};
  f32x4 lacc = (f32x4){0.f,0.f,0.f,0.f};
  float ll0v[4] = {0.f,0.f,0.f,0.f};
  float ll_mx = 0.f;
  float rsb_s = 0.f;
  uint32_t st0[8] = {0,0,0,0,0,0,0,0};   // band stashes (bf16 pairs), static idx only
  uint32_t st1[8] = {0,0,0,0,0,0,0,0};
  uint32_t st2[8] = {0,0,0,0,0,0,0,0};

  for (int kt = 0; kt < S_LEN; kt += 64){
    const int ktn = kt + 64;

    const bool leftC  = (kt <= q0 - 128);
    const bool rightC = (kt >= q0 + 128);
    const float qeadd = leftC ? qeL : (rightC ? qeR : 0.f);

    // QK^T from LDS K; C-init = mask(+qe)
    const u16* ks = uu.s.K;
    f32x4 p4[4];
    __builtin_amdgcn_s_setprio(1);
    #pragma unroll
    for (int fn = 0; fn < 4; ++fn){
      const u16* krow = ks + (fn * 16 + l15) * 64;
      short8 kb0 = *(const short8*)(krow + kO0);
      short8 kb1 = *(const short8*)(krow + kO1);
      f32x4 c = mcur[fn] + qeadd;
      c = MFMA(kb0, qa0, c);
      c = MFMA(kb1, qa1, c);
      p4[fn] = c;
    }
    __builtin_amdgcn_s_setprio(0);

    // prefetch next mask
    f32x4 mnext[4];
    if (ktn < S_LEN){
      #pragma unroll
      for (int fn = 0; fn < 4; ++fn) mnext[fn] = *(const f32x4*)(mBase + ktn + fn * 16 + rqb);
    }

    if (leftC | rightC){
      #pragma unroll
      for (int fn = 0; fn < 4; ++fn)
        #pragma unroll
        for (int r = 0; r < 4; ++r) p4[fn][r] = __builtin_amdgcn_exp2f(p4[fn][r]);
    } else {
      // mixed: per-element qe gather; band sums only (P stashed in PV pack below)
      #pragma unroll
      for (int fn = 0; fn < 4; ++fn){
        int kbase = kt + fn * 16 + rqb;
        #pragma unroll
        for (int r = 0; r < 4; ++r){
          int dq = qrow - (kbase + r) + 64;
          int ridx = min(max(dq, 0), 127);
          float qv = (dq >= 128) ? qeL : bf2f(qq.QEb[w][l15][ridx]);
          float p = __builtin_amdgcn_exp2f(p4[fn][r] + qv);
          ll_mx += (dq >= 128) ? p : 0.f;
          rsb_s += (dq >= 1 && dq <= 127) ? p : 0.f;
          p4[fn][r] = p;
        }
      }
    }

    // pack P, stash band tiles, MFMA row-sum, PV
    __builtin_amdgcn_s_setprio(1);
    const u16* vsb = uu.s.V;
    #pragma unroll
    for (int fp = 0; fp < 2; ++fp){
      union { uint32_t u[4]; short8 s8; } pk;
      pk.u[0] = cvtpk(p4[2 * fp][0],     p4[2 * fp][1]);
      pk.u[1] = cvtpk(p4[2 * fp][2],     p4[2 * fp][3]);
      pk.u[2] = cvtpk(p4[2 * fp + 1][0], p4[2 * fp + 1][1]);
      pk.u[3] = cvtpk(p4[2 * fp + 1][2], p4[2 * fp + 1][3]);
      if (kt == q0 - 64){
        #pragma unroll
        for (int u4 = 0; u4 < 4; ++u4) st0[fp * 4 + u4] = pk.u[u4];
      } else if (kt == q0){
        #pragma unroll
        for (int u4 = 0; u4 < 4; ++u4) st1[fp * 4 + u4] = pk.u[u4];
      } else if (kt == q0 + 64){
        #pragma unroll
        for (int u4 = 0; u4 < 4; ++u4) st2[fp * 4 + u4] = pk.u[u4];
      }
      short8 pa = pk.s8;
      lacc = MFMA(pa, bones, lacc);
      const int vO = fp ? vO1 : vO0;
      #pragma unroll
      for (int fd = 0; fd < 4; ++fd){
        short8 vb = *(const short8*)(vsb + (fd * 16 + l15) * 64 + vO);
        o[fd] = MFMA(pa, vb, o[fd]);
      }
    }
    __builtin_amdgcn_s_setprio(0);

    if (kt == q0 - 128){
      #pragma unroll
      for (int r = 0; r < 4; ++r) ll0v[r] = lacc[r];
    }
    if (ktn < S_LEN){
      #pragma unroll
      for (int fn = 0; fn < 4; ++fn) mcur[fn] = mnext[fn];
      __syncthreads();   // all reads of this tile done
      u16* kd = uu.s.K + (w * 16) * 64;
      u16* vd = uu.s.V + (w * 16) * 64;
      gl_lds16(kS + (size_t)ktn * 64,       kd);
      gl_lds16(kS + (size_t)(ktn + 8) * 64, kd + 512);
      gl_lds16(vS + ktn,                    vd);
      gl_lds16(vS + ktn + 8 * S_LEN,        vd + 512);
      __syncthreads();   // drains DMA -> next tile visible (TLP covers the stall)
    }
  }

  // ---- tail: overlay Psb/Evs onto dead LDS ----
  __syncthreads();   // all K/V & QEb reads complete before overwrite
  {
    short8 z8 = (short8){0,0,0,0,0,0,0,0};
    #pragma unroll
    for (int i = 0; i < 4; ++i) ((short8*)uu.Psb)[tid + i * 256] = z8;
    int d = tid & 63, t4 = tid >> 6;
    #pragma unroll
    for (int it = 0; it < 32; ++it){
      int t = t4 + it * 4;
      float v = (t <= 126) ? embv[(size_t)(127 - t) * 64 + d] : 0.f;
      qq.Evs[d][(((t >> 3) ^ (d & 7)) << 3) | (t & 7)] = f2bf(v);
    }
  }
  __syncthreads();

  // band writes from stash (swizzled Psb, same key as reads: row&7 = l15&7)
  auto bandw = [&](int ktb, const uint32_t* st){
    #pragma unroll
    for (int fn = 0; fn < 4; ++fn)
      #pragma unroll
      for (int r = 0; r < 4; ++r){
        int dq = qrow - (ktb + fn * 16 + rqb + r) + 64;
        if (dq >= 1 && dq <= 127){
          int t = 127 - dq;
          uu.Psb[wm + l15][(((t >> 3) ^ rsw) << 3) | (t & 7)] =
            (u16)(st[(fn >> 1) * 4 + (fn & 1) * 2 + (r >> 1)] >> ((r & 1) * 16));
        }
      }
  };
  if (q0 >= 64) bandw(q0 - 64, st0);
  bandw(q0, st1);
  if (q0 + 64 < S_LEN) bandw(q0 + 64, st2);
  __syncthreads();

  // tail MFMA: ob = Psb_band @ Evs
  f32x4 ob[4];
  #pragma unroll
  for (int f = 0; f < 4; ++f) ob[f] = (f32x4){0.f,0.f,0.f,0.f};
  #pragma unroll
  for (int kb = 0; kb < 4; ++kb){
    const int go = ((kb * 4 + quad) ^ rsw) << 3;
    short8 pa = *(const short8*)&uu.Psb[wm + l15][go];
    #pragma unroll
    for (int fd = 0; fd < 4; ++fd){
      short8 vb = *(const short8*)&qq.Evs[fd * 16 + l15][go];
      ob[fd] = MFMA(pa, vb, ob[fd]);
    }
  }

  // final reductions
  #pragma unroll
  for (int st = 16; st < 64; st <<= 1){
    ll_mx += __shfl_xor(ll_mx, st, 64);
    rsb_s += __shfl_xor(rsb_s, st, 64);
  }

  float inv[4], tl[4], trr[4];
  #pragma unroll
  for (int r = 0; r < 4; ++r){
    float L   = __shfl(lacc[r], quad << 4);
    float l0  = __shfl(ll0v[r], quad << 4);
    int src   = (quad << 4) + rqb + r;
    float lmx = __shfl(ll_mx, src);
    float rv  = __shfl(rsb_s, src);
    inv[r] = 1.f / L;
    tl[r]  = (l0 + lmx) * inv[r];
    trr[r] = 1.f - tl[r] - rv * inv[r];
  }

  #pragma unroll
  for (int fd = 0; fd < 4; ++fd){
    int dim = fd * 16 + l15;
    float evL = embv[(size_t)128 * 64 + dim];
    float evR = embv[dim];
    #pragma unroll
    for (int r = 0; r < 4; ++r){
      int row = q0 + wm + rqb + r;
      float val = (o[fd][r] + ob[fd][r]) * inv[r] + tl[r] * evL + trr[r] * evR;
      out[((size_t)(b * S_LEN + row)) * DMODEL + h * 64 + dim] = val;
    }
  }
}

extern "C" void kernel_launch(void* const* d_in, const int* in_sizes, int n_in,
                              void* d_out, int out_size, void* d_ws, size_t ws_size,
                              hipStream_t stream){
  const float* X    = (const float*)d_in[0];
  const float* mask = (const float*)d_in[1];
  const float* Wq   = (const float*)d_in[2];
  const float* bq   = (const float*)d_in[3];
  const float* Wk   = (const float*)d_in[4];
  const float* bk   = (const float*)d_in[5];
  const float* Wv   = (const float*)d_in[6];
  const float* bv   = (const float*)d_in[7];
  const float* embk = (const float*)d_in[8];
  const float* embv = (const float*)d_in[9];
  float* out = (float*)d_out;
  char* ws = (char*)d_ws;

  u16* XB   = (u16*)(ws + 0);            // 8,388,608
  u16* WT   = (u16*)(ws + 8388608);      // 6,291,456
  u16* EKB  = (u16*)(ws + 14680064);     // 18,432
  u16* QS   = (u16*)(ws + 14698496);     // 8,388,608
  u16* KB   = (u16*)(ws + 23087104);     // 8,388,608
  u16* VP   = (u16*)(ws + 31475712);     // 8,388,608 (transposed + PV-permuted V)
  float* MSL = (float*)(ws + 48252928);  // 16,384  (end 48,269,312)

  k_prep   <<<4916, 256, 0, stream>>>(X, Wq, Wk, Wv, embk, mask, XB, WT, EKB, MSL);
  k_qkv    <<<dim3(8, 32, 3), 256, 0, stream>>>(XB, WT, bq, bk, bv, QS, KB, VP);
  k_flash  <<<dim3(32, 32), 256, 0, stream>>>(QS, KB, VP, EKB, MSL, embv, out);
}